// Round 1
// baseline (103.539 us; speedup 1.0000x reference)
//
#include <hip/hip_runtime.h>
#include <math.h>

#define DDIM 512
#define BDIM 256
#define NCLS 85742

__device__ __forceinline__ float wave_reduce(float v) {
    #pragma unroll
    for (int off = 32; off > 0; off >>= 1)
        v += __shfl_down(v, off, 64);
    return v;
}

__device__ __forceinline__ float block_reduce(float v, float* smem) {
    const int lane = threadIdx.x & 63;
    const int wid  = threadIdx.x >> 6;
    v = wave_reduce(v);
    if (lane == 0) smem[wid] = v;
    __syncthreads();
    if (wid == 0) {
        v = (lane < (int)(blockDim.x >> 6)) ? smem[lane] : 0.0f;
        v = wave_reduce(v);
    }
    return v;
}

// K1: colsum[d] = sum_c W[c][d].  256 threads/block, each owns a float2 (2 cols).
__global__ void colsum_kernel(const float* __restrict__ W,
                              float* __restrict__ colsum) {
    const int t = threadIdx.x;           // 0..255, col pair 2t,2t+1
    float2 acc = make_float2(0.0f, 0.0f);
    for (int r = blockIdx.x; r < NCLS; r += gridDim.x) {
        const float2* row = reinterpret_cast<const float2*>(W + (size_t)r * DDIM);
        float2 v = row[t];
        acc.x += v.x;
        acc.y += v.y;
    }
    atomicAdd(&colsum[2 * t],     acc.x);
    atomicAdd(&colsum[2 * t + 1], acc.y);
}

// K2: Sy = sum (wy-mu)^2 ; Si = sum (colsum - wy - mu)^2   over B*D elements
__global__ void dist_kernel(const float* __restrict__ mu,
                            const float* __restrict__ W,
                            const int*   __restrict__ label,
                            const float* __restrict__ colsum,
                            float* __restrict__ sums) {
    __shared__ float smem[8];
    float dy2 = 0.0f, di2 = 0.0f;
    const int n = BDIM * DDIM;
    for (int i = blockIdx.x * blockDim.x + threadIdx.x; i < n;
         i += gridDim.x * blockDim.x) {
        const int b = i >> 9;        // i / 512
        const int d = i & 511;       // i % 512
        const float w = W[(size_t)label[b] * DDIM + d];
        const float m = mu[i];
        const float a = w - m;
        dy2 += a * a;
        const float c = colsum[d] - w - m;
        di2 += c * c;
    }
    dy2 = block_reduce(dy2, smem);
    __syncthreads();
    di2 = block_reduce(di2, smem);
    if (threadIdx.x == 0) {
        atomicAdd(&sums[0], dy2);
        atomicAdd(&sums[1], di2);
    }
}

// K3: loss = sum erf(dy/(sqrt2*std)) + erfc(di/(sqrt2*std))
__global__ void loss_kernel(const float* __restrict__ stdv,
                            const float* __restrict__ sums,
                            float* __restrict__ out) {
    __shared__ float smem[8];
    const float dy = sqrtf(sums[0]);
    const float di = sqrtf(sums[1]);
    const float inv_sqrt2 = 0.70710678118654752f;
    float acc = 0.0f;
    const int n = BDIM * DDIM;
    for (int i = blockIdx.x * blockDim.x + threadIdx.x; i < n;
         i += gridDim.x * blockDim.x) {
        const float s = stdv[i];
        const float r = inv_sqrt2 / s;
        acc += erff(dy * r) + erfcf(di * r);
    }
    acc = block_reduce(acc, smem);
    if (threadIdx.x == 0) atomicAdd(out, acc);
}

extern "C" void kernel_launch(void* const* d_in, const int* in_sizes, int n_in,
                              void* d_out, int out_size, void* d_ws, size_t ws_size,
                              hipStream_t stream) {
    // inputs: 0=x (unused), 1=mu, 2=std, 3=weight, 4=label
    const float* mu    = (const float*)d_in[1];
    const float* stdv  = (const float*)d_in[2];
    const float* W     = (const float*)d_in[3];
    const int*   label = (const int*)d_in[4];
    float* out = (float*)d_out;
    float* ws  = (float*)d_ws;   // ws[0..511]=colsum, ws[512]=Sy, ws[513]=Si

    hipMemsetAsync(d_ws, 0, (DDIM + 2) * sizeof(float), stream);
    hipMemsetAsync(d_out, 0, sizeof(float), stream);

    colsum_kernel<<<1024, 256, 0, stream>>>(W, ws);
    dist_kernel<<<256, 256, 0, stream>>>(mu, W, label, ws, ws + DDIM);
    loss_kernel<<<256, 256, 0, stream>>>(stdv, ws + DDIM, out);
}